// Round 4
// baseline (884.747 us; speedup 1.0000x reference)
//
#include <hip/hip_runtime.h>
#include <math.h>

#define NN 50000
#define NE 800000

typedef __attribute__((ext_vector_type(8))) short bf8;   // 8 bf16 = 4 VGPRs (MFMA A/B frag)
typedef __attribute__((ext_vector_type(4))) float f32x4; // MFMA C/D frag
typedef unsigned int u32;
typedef unsigned long long u64;

__device__ __forceinline__ unsigned short f2b(float f){
  union{float f;unsigned u;} v; v.f=f;
  unsigned r=v.u+0x7fff+((v.u>>16)&1u);
  return (unsigned short)(r>>16);
}
__device__ __forceinline__ float b2f(unsigned short h){
  union{unsigned u;float f;} v; v.u=((unsigned)h)<<16; return v.f;
}
__device__ __forceinline__ float lo_bf(u32 t){ union{u32 u;float f;} v; v.u=t<<16; return v.f; }
__device__ __forceinline__ float hi_bf(u32 t){ union{u32 u;float f;} v; v.u=t&0xffff0000u; return v.f; }
// fast transcendentals: v_exp_f32 + v_rcp_f32 (error ~1e-6, far below bf16 noise)
__device__ __forceinline__ float fsigm(float x){ return __builtin_amdgcn_rcpf(1.f+__expf(-x)); }
__device__ __forceinline__ float ftanh(float x){ return 1.f-2.f*__builtin_amdgcn_rcpf(__expf(2.f*x)+1.f); }

// async global->LDS, 16B per lane. LDS dest = wave-uniform base + lane*16.
__device__ __forceinline__ void gload16(const unsigned short* g, unsigned short* l){
  __builtin_amdgcn_global_load_lds((const __attribute__((address_space(1))) u32*)g,
                                   (__attribute__((address_space(3))) u32*)l,
                                   16,0,0);
}

__device__ __forceinline__ int wscan_incl(int v,int lane){
  #pragma unroll
  for(int d=1;d<64;d<<=1){ int t=__shfl_up(v,d,64); if(lane>=d)v+=t; }
  return v;
}

// ---------- graph preprocessing ----------
__global__ __launch_bounds__(256) void k_init(float* deg,int* cnt,float* colsum,float* colsq){
  int i=blockIdx.x*256+threadIdx.x;
  if(i<NN){deg[i]=1.0f;cnt[i]=0;}
  if(i<256){colsum[i]=0.f;colsq[i]=0.f;}
}

__global__ __launch_bounds__(256) void k_deg(const int* __restrict__ ei,const float* __restrict__ ew,
                                             float* deg,int* cnt){
  int e=blockIdx.x*256+threadIdx.x;
  if(e<NE){int d=ei[NE+e];atomicAdd(&deg[d],ew[e]);atomicAdd(&cnt[d],1);}
}

__global__ __launch_bounds__(256) void k_dinv(const float* __restrict__ deg,float* dinv){
  int i=blockIdx.x*256+threadIdx.x;
  if(i<NN){float d=deg[i];dinv[i]=d>0.f?rsqrtf(d):0.f;}
}

// 3-phase scan: per-block shuffle scan -> block-sum scan -> add base
__global__ __launch_bounds__(1024) void k_scan1(const int* __restrict__ cnt,int* row_ptr,int* bsum){
  __shared__ int wsum[16];
  __shared__ int woff[17];
  int tid=threadIdx.x,lane=tid&63,w=tid>>6;
  int i=blockIdx.x*1024+tid;
  int v=(i<NN)?cnt[i]:0;
  int incl=wscan_incl(v,lane);
  if(lane==63)wsum[w]=incl;
  __syncthreads();
  if(w==0){
    int t=(lane<16)?wsum[lane]:0;
    int s=wscan_incl(t,lane);
    if(lane<16)woff[lane+1]=s;
    if(lane==0)woff[0]=0;
  }
  __syncthreads();
  int excl=incl-v+woff[w];
  if(i<NN)row_ptr[i]=excl;
  if(tid==0)bsum[blockIdx.x]=woff[16];
}
__global__ __launch_bounds__(64) void k_scan2(int* bsum,int* bbase,int* row_ptr,int nblk){
  int tid=threadIdx.x;
  int v=(tid<nblk)?bsum[tid]:0;
  int incl=wscan_incl(v,tid);
  bbase[tid]=incl-v;
  if(tid==63)row_ptr[NN]=incl;
}
__global__ __launch_bounds__(256) void k_scan3(int* row_ptr,int* cursor,const int* __restrict__ bbase){
  int i=blockIdx.x*256+threadIdx.x;
  if(i<NN){
    int r=row_ptr[i]+bbase[i>>10];
    row_ptr[i]=r;cursor[i]=r;
  }
}

// scatter edges into CSR as packed int2{src, w_bits}
__global__ __launch_bounds__(256) void k_scatter(const int* __restrict__ ei,const float* __restrict__ ew,
    const float* __restrict__ dinv,int* cursor,int2* csr_sw){
  int e=blockIdx.x*256+threadIdx.x;
  if(e<NE){
    int s=ei[e],d=ei[NE+e];
    float wv=dinv[s]*ew[e]*dinv[d];
    int p=atomicAdd(&cursor[d],1);
    int2 o;o.x=s;o.y=__float_as_int(wv);
    csr_sw[p]=o;
  }
}

// ---------- weight / input prep ----------
__global__ __launch_bounds__(256) void k_wt(const float* __restrict__ W,unsigned short* __restrict__ Wt){
  int j=blockIdx.x,k=threadIdx.x;
  Wt[j*256+k]=f2b(W[k*256+j]);
}
__global__ __launch_bounds__(256) void k_f2b(const float* __restrict__ s,unsigned short* __restrict__ d,int n){
  int i=blockIdx.x*256+threadIdx.x;
  if(i<n)d[i]=f2b(s[i]);
}
__global__ __launch_bounds__(256) void k_cast(const float* __restrict__ s,unsigned short* __restrict__ d){
  long i=(long)blockIdx.x*256+threadIdx.x;   // one float4 -> ushort4 per thread
  float4 v=*(const float4*)&s[i*4];
  ushort4 o;o.x=f2b(v.x);o.y=f2b(v.y);o.z=f2b(v.z);o.w=f2b(v.w);
  *(ushort4*)&d[i*4]=o;
}
__global__ __launch_bounds__(256) void k_bsum(const float* __restrict__ a,const float* __restrict__ b,
                                              float* __restrict__ s,int n){
  int i=blockIdx.x*256+threadIdx.x;
  if(i<n)s[i]=a[i]+b[i];
}

// fold BN scale into GEMM weight (transposed, from fp32) + shift matvec tw[j]=sum_k shift[k]*W[k][j]
__global__ __launch_bounds__(256) void k_foldw(const float* __restrict__ W,
    const float* __restrict__ scale,const float* __restrict__ shift,
    unsigned short* __restrict__ Wt,float* __restrict__ tw){
  __shared__ float red[256];
  int j=blockIdx.x,k=threadIdx.x;
  float w=W[k*256+j];
  Wt[j*256+k]=f2b(w*scale[k]);
  red[k]=w*shift[k];
  __syncthreads();
  for(int off=128;off>0;off>>=1){ if(k<off)red[k]+=red[k+off]; __syncthreads(); }
  if(k==0)tw[j]=red[0];
}

// fold BN scale/shift (per input col) into LSTM ih weights + fused bias
__global__ __launch_bounds__(256) void k_foldlstm(const float* __restrict__ Wih,int K,
    const float* __restrict__ scale,const float* __restrict__ shift,
    const float* __restrict__ bih,const float* __restrict__ bhh,
    unsigned short* __restrict__ Wb,float* __restrict__ bs){
  __shared__ float red[256];
  int m=blockIdx.x,t=threadIdx.x;
  float part=0.f;
  for(int k=t;k<K;k+=256){
    float w=Wih[(long)m*K+k];
    Wb[(long)m*K+k]=f2b(w*scale[k]);
    part+=w*shift[k];
  }
  red[t]=part;
  __syncthreads();
  for(int off=128;off>0;off>>=1){ if(t<off)red[t]+=red[t+off]; __syncthreads(); }
  if(t==0)bs[m]=bih[m]+bhh[m]+red[0];
}

// ---------- dense MFMA GEMM: T8[chunk][node][32](bf16) = A[M,K] @ Bt^T (Bt is [256][K] bf16) ----------
__global__ __launch_bounds__(256,2) void k_gemm_mfma(
    const unsigned short* __restrict__ A,int lda,const unsigned short* __restrict__ Bt,int K,
    unsigned short* __restrict__ Cb){
  __shared__ unsigned short As[2][4096];   // 128 rows x 32 k
  __shared__ unsigned short Bs[2][4096];
  int tid=threadIdx.x;
  int row0=blockIdx.x*128,col0=blockIdx.y*128;
  int lane=tid&63,l15=lane&15,quad=lane>>4;
  int wid=tid>>6,wm=wid>>1,wn=wid&1;
  int sr=tid>>2;                           // staging row 0..63 (per 64-row half)
  int aoff=((tid&3)^((tid>>3)&3))*8;       // pre-swizzled source chunk offset (ushorts)
  int xq=quad^((l15>>1)&3);                // read-side physical chunk
  long ar0=row0+sr;    if(ar0>=NN)ar0=NN-1;
  long ar1=row0+64+sr; if(ar1>=NN)ar1=NN-1;
  const unsigned short* a0p=A+ar0*lda+aoff;
  const unsigned short* a1p=A+ar1*lda+aoff;
  const unsigned short* b0p=Bt+(long)(col0+sr)*K+aoff;
  const unsigned short* b1p=Bt+(long)(col0+64+sr)*K+aoff;
  int lb=wid*512;                          // wave-uniform LDS base (ushorts)
  f32x4 acc[4][4]={};
  int nt=K/32;
  gload16(a0p,&As[0][lb]); gload16(a1p,&As[0][2048+lb]);
  gload16(b0p,&Bs[0][lb]); gload16(b1p,&Bs[0][2048+lb]);
  __syncthreads();
  for(int t=0;t<nt;t++){
    int cur=t&1;
    if(t+1<nt){
      int k0=(t+1)*32;int nxt=cur^1;
      gload16(a0p+k0,&As[nxt][lb]); gload16(a1p+k0,&As[nxt][2048+lb]);
      gload16(b0p+k0,&Bs[nxt][lb]); gload16(b1p+k0,&Bs[nxt][2048+lb]);
    }
    bf8 af[4],bfg[4];
    #pragma unroll
    for(int i=0;i<4;i++){
      af[i] =*(const bf8*)&As[cur][(wm*64+i*16+l15)*32+xq*8];
      bfg[i]=*(const bf8*)&Bs[cur][(wn*64+i*16+l15)*32+xq*8];
    }
    #pragma unroll
    for(int mi=0;mi<4;mi++)
      #pragma unroll
      for(int ni=0;ni<4;ni++)
        acc[mi][ni]=__builtin_amdgcn_mfma_f32_16x16x32_bf16(af[mi],bfg[ni],acc[mi][ni],0,0,0);
    __syncthreads();
  }
  #pragma unroll
  for(int mi=0;mi<4;mi++){
    #pragma unroll
    for(int r=0;r<4;r++){
      int node=row0+wm*64+mi*16+quad*4+r;
      if(node>=NN)continue;
      #pragma unroll
      for(int ni=0;ni<4;ni++){
        int col=col0+wn*64+ni*16+l15;
        Cb[((size_t)(col>>5)*NN+node)*32+(col&31)]=f2b(acc[mi][ni][r]);  // chunk-major
      }
    }
  }
}

// ---------- fused 3-gate LSTM MFMA: h = sig(o)*tanh(sig(i)*tanh(g)) ----------
__global__ __launch_bounds__(256,2) void k_lstm_mfma(
    const unsigned short* __restrict__ A,int lda,int K,
    const unsigned short* __restrict__ Wb,const float* __restrict__ bsum,
    float* __restrict__ Hout,int ldh,unsigned short* __restrict__ Hb){
  __shared__ unsigned short As[2][4096];   // 128 rows x 32 k
  __shared__ unsigned short Bs[2][6144];   // 3 gates x 64 rows x 32 k
  int tid=threadIdx.x;
  int row0=blockIdx.x*128,m0=blockIdx.y*64;
  int lane=tid&63,l15=lane&15,quad=lane>>4;
  int wid=tid>>6,wm=wid>>1,wn=wid&1;
  int sr=tid>>2;
  int aoff=((tid&3)^((tid>>3)&3))*8;
  int xq=quad^((l15>>1)&3);
  long ar0=row0+sr;    if(ar0>=NN)ar0=NN-1;
  long ar1=row0+64+sr; if(ar1>=NN)ar1=NN-1;
  const unsigned short* a0p=A+ar0*lda+aoff;
  const unsigned short* a1p=A+ar1*lda+aoff;
  const unsigned short* wip=Wb+(long)(    m0+sr)*K+aoff;   // i gate
  const unsigned short* wgp=Wb+(long)(512+m0+sr)*K+aoff;   // g gate
  const unsigned short* wop=Wb+(long)(768+m0+sr)*K+aoff;   // o gate
  int lb=wid*512;
  f32x4 ai[4][2]={},ag[4][2]={},ao[4][2]={};
  int nt=K/32;
  gload16(a0p,&As[0][lb]); gload16(a1p,&As[0][2048+lb]);
  gload16(wip,&Bs[0][lb]); gload16(wgp,&Bs[0][2048+lb]); gload16(wop,&Bs[0][4096+lb]);
  __syncthreads();
  for(int t=0;t<nt;t++){
    int cur=t&1;
    if(t+1<nt){
      int k0=(t+1)*32;int nxt=cur^1;
      gload16(a0p+k0,&As[nxt][lb]); gload16(a1p+k0,&As[nxt][2048+lb]);
      gload16(wip+k0,&Bs[nxt][lb]); gload16(wgp+k0,&Bs[nxt][2048+lb]); gload16(wop+k0,&Bs[nxt][4096+lb]);
    }
    bf8 af[4],bi[2],bg[2],bo[2];
    #pragma unroll
    for(int i=0;i<4;i++)af[i]=*(const bf8*)&As[cur][(wm*64+i*16+l15)*32+xq*8];
    #pragma unroll
    for(int ni=0;ni<2;ni++){
      int rr=wn*32+ni*16+l15;
      bi[ni]=*(const bf8*)&Bs[cur][(    rr)*32+xq*8];
      bg[ni]=*(const bf8*)&Bs[cur][( 64+rr)*32+xq*8];
      bo[ni]=*(const bf8*)&Bs[cur][(128+rr)*32+xq*8];
    }
    #pragma unroll
    for(int mi=0;mi<4;mi++)
      #pragma unroll
      for(int ni=0;ni<2;ni++){
        ai[mi][ni]=__builtin_amdgcn_mfma_f32_16x16x32_bf16(af[mi],bi[ni],ai[mi][ni],0,0,0);
        ag[mi][ni]=__builtin_amdgcn_mfma_f32_16x16x32_bf16(af[mi],bg[ni],ag[mi][ni],0,0,0);
        ao[mi][ni]=__builtin_amdgcn_mfma_f32_16x16x32_bf16(af[mi],bo[ni],ao[mi][ni],0,0,0);
      }
    __syncthreads();
  }
  #pragma unroll
  for(int ni=0;ni<2;ni++){
    int m=m0+wn*32+ni*16+l15;
    float b_i=bsum[m],b_g=bsum[512+m],b_o=bsum[768+m];
    #pragma unroll
    for(int mi=0;mi<4;mi++){
      #pragma unroll
      for(int r=0;r<4;r++){
        int node=row0+wm*64+mi*16+quad*4+r;
        if(node>=NN)continue;
        float gi=ai[mi][ni][r]+b_i;
        float gg=ag[mi][ni][r]+b_g;
        float go=ao[mi][ni][r]+b_o;
        float c=fsigm(gi)*ftanh(gg);
        float h=fsigm(go)*ftanh(c);
        Hout[(long)node*ldh+m]=h;
        if(Hb)Hb[(long)node*256+m]=f2b(h);
      }
    }
  }
}

// ---------- chunked SpMM: T8[chunk][node][32] bf16, chunk = blockIdx&7 -> XCD-pinned L2 slice ----------
// Block: 4 waves x (4 rows x 16 lanes x 2 cols). 16 rows/block, 3125 row-blocks x 8 chunks.
__global__ __launch_bounds__(256) void k_spmm8(const unsigned short* __restrict__ T8,
    const int* __restrict__ row_ptr,const int2* __restrict__ csr_sw,
    const float* __restrict__ dinv,const float* __restrict__ bias,const float* __restrict__ tw,
    unsigned short* __restrict__ Xb,float* colsum,float* colsq){
  __shared__ float4 s_red[4][16];
  int tid=threadIdx.x;
  int lane=tid&63,wv=tid>>6;
  int g=lane>>4,li=lane&15;
  int chunk=blockIdx.x&7;
  int rowblk=blockIdx.x>>3;
  int r=rowblk*16+wv*4+g;              // 3125*16 == NN exactly: always valid
  int li2=li*2;
  int c0=chunk*32+li2;
  const unsigned short* Tc=T8+(size_t)chunk*NN*32;
  int p0=row_ptr[r],p1=row_ptr[r+1];
  int len=p1-p0;
  float di=dinv[r],ws=di*di;
  float rs=ws;
  u32 ts=*(const u32*)&Tc[(size_t)r*32+li2];
  float acc0=ws*lo_bf(ts),acc1=ws*hi_bf(ts);
  // wave-wide max length across the 4 row-groups
  int Lm=len;
  Lm=max(Lm,__shfl_xor(Lm,16,64));
  Lm=max(Lm,__shfl_xor(Lm,32,64));
  for(int j=0;j<Lm;j+=4){
    #pragma unroll
    for(int u=0;u<4;u++){
      int jj=j+u;
      bool act=jj<len;
      int idx=p0+(act?jj:0);
      idx=min(idx,NE-1);
      u64 ev=__builtin_nontemporal_load((const u64*)&csr_sw[idx]);
      int s=(int)(u32)ev;
      float wgt=act?__int_as_float((int)(ev>>32)):0.f;
      s=min(max(s,0),NN-1);
      u32 t=*(const u32*)&Tc[(size_t)s*32+li2];
      acc0+=wgt*lo_bf(t);
      acc1+=wgt*hi_bf(t);
      rs+=wgt;
    }
  }
  float tw0=0.f,tw1=0.f;
  if(tw){ float2 tc=*(const float2*)&tw[c0]; tw0=tc.x; tw1=tc.y; }
  float2 bc=*(const float2*)&bias[c0];
  float a0=fmaxf(acc0+rs*tw0+bc.x,0.f);
  float a1=fmaxf(acc1+rs*tw1+bc.y,0.f);
  u32 o=(u32)f2b(a0)|((u32)f2b(a1)<<16);
  __builtin_nontemporal_store(o,(u32*)&Xb[(size_t)r*512+c0]);
  // stats: reduce across 4 row-groups, then waves, then one atomic set per block
  float s0=a0,s1=a1,q0=a0*a0,q1=a1*a1;
  #pragma unroll
  for(int m=16;m<=32;m<<=1){
    s0+=__shfl_xor(s0,m,64); s1+=__shfl_xor(s1,m,64);
    q0+=__shfl_xor(q0,m,64); q1+=__shfl_xor(q1,m,64);
  }
  if(lane<16)s_red[wv][lane]=make_float4(s0,s1,q0,q1);
  __syncthreads();
  if(tid<16){
    float4 a=s_red[0][tid],b=s_red[1][tid],c=s_red[2][tid],d=s_red[3][tid];
    float f0=a.x+b.x+c.x+d.x;
    float f1=a.y+b.y+c.y+d.y;
    float f2=a.z+b.z+c.z+d.z;
    float f3=a.w+b.w+c.w+d.w;
    int cc=chunk*32+tid*2;
    atomicAdd(&colsum[cc],f0);atomicAdd(&colsum[cc+1],f1);
    atomicAdd(&colsq[cc],f2);atomicAdd(&colsq[cc+1],f3);
  }
}

__global__ __launch_bounds__(256) void k_bnfin(const float* __restrict__ gamma,const float* __restrict__ beta,
    float* colsum,float* colsq,float* scale,float* shift){
  int c=threadIdx.x;
  float mu=colsum[c]/(float)NN;
  float var=colsq[c]/(float)NN-mu*mu;
  float r=rsqrtf(var+1e-5f);
  float sc=r*gamma[c];
  scale[c]=sc;
  shift[c]=beta[c]-mu*sc;
  colsum[c]=0.f;colsq[c]=0.f;
}

__global__ __launch_bounds__(256) void k_copy_out(const float* __restrict__ src,
    float* __restrict__ out,int colofs){
  long idx=(long)blockIdx.x*256+threadIdx.x;
  long r=idx>>6;int cc=(int)(idx&63)*4;
  if(r<NN)*(float4*)&out[r*768+colofs+cc]=*(const float4*)&src[r*256+cc];
}

extern "C" void kernel_launch(void* const* d_in,const int* in_sizes,int n_in,
                              void* d_out,int out_size,void* d_ws,size_t ws_size,
                              hipStream_t stream){
  const float* x   =(const float*)d_in[0];
  const int*   ei  =(const int*)  d_in[1];
  const float* ew  =(const float*)d_in[2];
  const float* W1  =(const float*)d_in[3];
  const float* b1  =(const float*)d_in[4];
  const float* W2  =(const float*)d_in[5];
  const float* b2  =(const float*)d_in[6];
  const float* g1  =(const float*)d_in[7];
  const float* be1 =(const float*)d_in[8];
  const float* g2  =(const float*)d_in[9];
  const float* be2 =(const float*)d_in[10];
  const float* Wih1=(const float*)d_in[11];
  const float* bih1=(const float*)d_in[13];
  const float* bhh1=(const float*)d_in[14];
  const float* Wih2=(const float*)d_in[15];
  const float* bih2=(const float*)d_in[17];
  const float* bhh2=(const float*)d_in[18];
  float* out=(float*)d_out;

  char* w=(char*)d_ws;
  auto alloc=[&](size_t bytes)->char*{char* p=w;w+=(bytes+255)&~(size_t)255;return p;};
  float* deg    =(float*)alloc((size_t)NN*4);
  float* dinv   =(float*)alloc((size_t)NN*4);
  int*   cnt    =(int*)  alloc((size_t)NN*4);
  int*   row_ptr=(int*)  alloc((size_t)(NN+1)*4);
  int*   cursor =(int*)  alloc((size_t)NN*4);
  int2*  csr_sw =(int2*) alloc((size_t)NE*8);
  int*   bsum_s =(int*)  alloc(64*4);
  int*   bbase  =(int*)  alloc(64*4);
  float* colsum =(float*)alloc(256*4);
  float* colsq  =(float*)alloc(256*4);
  float* scale  =(float*)alloc(512*4);
  float* shift  =(float*)alloc(512*4);
  float* tw     =(float*)alloc(256*4);
  unsigned short* Xcb =(unsigned short*)alloc((size_t)NN*512*2);  // [h1pre|h2pre] bf16, ld 512
  unsigned short* TbH =(unsigned short*)alloc((size_t)NN*256*2);  // chunk-major GEMM out / LSTM1 hidden (row-major, aliased)
  unsigned short* xb  =(unsigned short*)alloc((size_t)NN*256*2);  // x cast to bf16
  unsigned short* Wt1 =(unsigned short*)alloc(256*256*2);
  unsigned short* Wt2 =(unsigned short*)alloc(256*256*2);
  unsigned short* Wb1 =(unsigned short*)alloc((size_t)1024*512*2);
  unsigned short* Wb2 =(unsigned short*)alloc((size_t)1024*256*2);
  float* bs1 =(float*)alloc(1024*4);
  float* bs2 =(float*)alloc(1024*4);

  int nb=(NN+255)/256;
  int nsc=(NN+1023)/1024;   // 49
  k_init<<<nb,256,0,stream>>>(deg,cnt,colsum,colsq);
  k_deg<<<(NE+255)/256,256,0,stream>>>(ei,ew,deg,cnt);
  k_dinv<<<nb,256,0,stream>>>(deg,dinv);
  k_scan1<<<nsc,1024,0,stream>>>(cnt,row_ptr,bsum_s);
  k_scan2<<<1,64,0,stream>>>(bsum_s,bbase,row_ptr,nsc);
  k_scan3<<<nb,256,0,stream>>>(row_ptr,cursor,bbase);
  k_scatter<<<(NE+255)/256,256,0,stream>>>(ei,ew,dinv,cursor,csr_sw);

  k_wt<<<256,256,0,stream>>>(W1,Wt1);
  k_cast<<<12500,256,0,stream>>>(x,xb);      // 50000*256/4 threads exactly
  k_f2b<<<(1024*256+255)/256,256,0,stream>>>(Wih2,Wb2,1024*256);
  k_bsum<<<4,256,0,stream>>>(bih2,bhh2,bs2,1024);

  int ngx=(NN+127)/128;
  dim3 gd(ngx,2);   // dense GEMM: 256 cols / 128
  dim3 gl(ngx,4);   // lstm: 256 h-cols / 64
  int nspmm=8*(NN/16);   // 8 chunks x 3125 row-blocks

  // layer 1 (Xcb[0:256) holds PRE-BN relu'd h1; BN folded into downstream consumers)
  k_gemm_mfma<<<gd,256,0,stream>>>(xb,256,Wt1,256,TbH);
  k_spmm8<<<nspmm,256,0,stream>>>(TbH,row_ptr,csr_sw,dinv,b1,nullptr,Xcb+0,colsum,colsq);
  k_bnfin<<<1,256,0,stream>>>(g1,be1,colsum,colsq,scale,shift);
  // fold BN1 into GEMM2 weights; shift contribution handled via rowsum*tw in spmm2
  k_foldw<<<256,256,0,stream>>>(W2,scale,shift,Wt2,tw);
  // layer 2 (Xcb[256:512) holds PRE-BN relu'd h2)
  k_gemm_mfma<<<gd,256,0,stream>>>(Xcb,512,Wt2,256,TbH);
  k_spmm8<<<nspmm,256,0,stream>>>(TbH,row_ptr,csr_sw,dinv,b2,tw,Xcb+256,colsum,colsq);
  k_bnfin<<<1,256,0,stream>>>(g2,be2,colsum,colsq,scale+256,shift+256);
  // fold BN1|BN2 (concat cols) into LSTM1 ih weights + fused bias
  k_foldlstm<<<1024,256,0,stream>>>(Wih1,512,scale,shift,bih1,bhh1,Wb1,bs1);
  // LSTM1: A=Xcb [N,512] pre-BN -> out[0:256) fp32 + TbH bf16 (TbH dead after spmm2)
  k_lstm_mfma<<<gl,256,0,stream>>>(Xcb,512,512,Wb1,bs1,out+0,768,TbH);
  // LSTM2: A=TbH [N,256] -> out[256:512)
  k_lstm_mfma<<<gl,256,0,stream>>>(TbH,256,256,Wb2,bs2,out+256,768,nullptr);
  // x passthrough
  k_copy_out<<<12500,256,0,stream>>>(x,out,512);
}

// Round 5
// 779.780 us; speedup vs baseline: 1.1346x; 1.1346x over previous
//
#include <hip/hip_runtime.h>
#include <math.h>

#define NN 50000
#define NE 800000

typedef __attribute__((ext_vector_type(8))) short bf8;   // 8 bf16 = 4 VGPRs (MFMA A/B frag)
typedef __attribute__((ext_vector_type(4))) float f32x4; // MFMA C/D frag
typedef unsigned int u32;
typedef unsigned long long u64;

__device__ __forceinline__ unsigned short f2b(float f){
  union{float f;unsigned u;} v; v.f=f;
  unsigned r=v.u+0x7fff+((v.u>>16)&1u);
  return (unsigned short)(r>>16);
}
__device__ __forceinline__ float b2f(unsigned short h){
  union{unsigned u;float f;} v; v.u=((unsigned)h)<<16; return v.f;
}
// fast transcendentals: v_exp_f32 + v_rcp_f32 (error ~1e-6, far below bf16 noise)
__device__ __forceinline__ float fsigm(float x){ return __builtin_amdgcn_rcpf(1.f+__expf(-x)); }
__device__ __forceinline__ float ftanh(float x){ return 1.f-2.f*__builtin_amdgcn_rcpf(__expf(2.f*x)+1.f); }

// async global->LDS, 16B per lane. LDS dest = wave-uniform base + lane*16.
__device__ __forceinline__ void gload16(const unsigned short* g, unsigned short* l){
  __builtin_amdgcn_global_load_lds((const __attribute__((address_space(1))) u32*)g,
                                   (__attribute__((address_space(3))) u32*)l,
                                   16,0,0);
}

__device__ __forceinline__ int wscan_incl(int v,int lane){
  #pragma unroll
  for(int d=1;d<64;d<<=1){ int t=__shfl_up(v,d,64); if(lane>=d)v+=t; }
  return v;
}

// ---------- graph preprocessing ----------
__global__ __launch_bounds__(256) void k_init(float* deg,int* cnt,float* colsum,float* colsq){
  int i=blockIdx.x*256+threadIdx.x;
  if(i<NN){deg[i]=1.0f;cnt[i]=0;}
  if(i<256){colsum[i]=0.f;colsq[i]=0.f;}
}

__global__ __launch_bounds__(256) void k_deg(const int* __restrict__ ei,const float* __restrict__ ew,
                                             float* deg,int* cnt){
  int e=blockIdx.x*256+threadIdx.x;
  if(e<NE){int d=ei[NE+e];atomicAdd(&deg[d],ew[e]);atomicAdd(&cnt[d],1);}
}

__global__ __launch_bounds__(256) void k_dinv(const float* __restrict__ deg,float* dinv){
  int i=blockIdx.x*256+threadIdx.x;
  if(i<NN){float d=deg[i];dinv[i]=d>0.f?rsqrtf(d):0.f;}
}

// 3-phase scan: per-block shuffle scan -> block-sum scan -> add base
__global__ __launch_bounds__(1024) void k_scan1(const int* __restrict__ cnt,int* row_ptr,int* bsum){
  __shared__ int wsum[16];
  __shared__ int woff[17];
  int tid=threadIdx.x,lane=tid&63,w=tid>>6;
  int i=blockIdx.x*1024+tid;
  int v=(i<NN)?cnt[i]:0;
  int incl=wscan_incl(v,lane);
  if(lane==63)wsum[w]=incl;
  __syncthreads();
  if(w==0){
    int t=(lane<16)?wsum[lane]:0;
    int s=wscan_incl(t,lane);
    if(lane<16)woff[lane+1]=s;
    if(lane==0)woff[0]=0;
  }
  __syncthreads();
  int excl=incl-v+woff[w];
  if(i<NN)row_ptr[i]=excl;
  if(tid==0)bsum[blockIdx.x]=woff[16];
}
__global__ __launch_bounds__(64) void k_scan2(int* bsum,int* bbase,int* row_ptr,int nblk){
  int tid=threadIdx.x;
  int v=(tid<nblk)?bsum[tid]:0;
  int incl=wscan_incl(v,tid);
  bbase[tid]=incl-v;
  if(tid==63)row_ptr[NN]=incl;
}
__global__ __launch_bounds__(256) void k_scan3(int* row_ptr,int* cursor,const int* __restrict__ bbase){
  int i=blockIdx.x*256+threadIdx.x;
  if(i<NN){
    int r=row_ptr[i]+bbase[i>>10];
    row_ptr[i]=r;cursor[i]=r;
  }
}

// scatter edges into CSR as packed int2{src, w_bits}
__global__ __launch_bounds__(256) void k_scatter(const int* __restrict__ ei,const float* __restrict__ ew,
    const float* __restrict__ dinv,int* cursor,int2* csr_sw){
  int e=blockIdx.x*256+threadIdx.x;
  if(e<NE){
    int s=ei[e],d=ei[NE+e];
    float wv=dinv[s]*ew[e]*dinv[d];
    int p=atomicAdd(&cursor[d],1);
    int2 o;o.x=s;o.y=__float_as_int(wv);
    csr_sw[p]=o;
  }
}

// ---------- weight / input prep ----------
__global__ __launch_bounds__(256) void k_wt(const float* __restrict__ W,unsigned short* __restrict__ Wt){
  int j=blockIdx.x,k=threadIdx.x;
  Wt[j*256+k]=f2b(W[k*256+j]);
}
__global__ __launch_bounds__(256) void k_f2b(const float* __restrict__ s,unsigned short* __restrict__ d,int n){
  int i=blockIdx.x*256+threadIdx.x;
  if(i<n)d[i]=f2b(s[i]);
}
__global__ __launch_bounds__(256) void k_cast(const float* __restrict__ s,unsigned short* __restrict__ d){
  long i=(long)blockIdx.x*256+threadIdx.x;   // one float4 -> ushort4 per thread
  float4 v=*(const float4*)&s[i*4];
  ushort4 o;o.x=f2b(v.x);o.y=f2b(v.y);o.z=f2b(v.z);o.w=f2b(v.w);
  *(ushort4*)&d[i*4]=o;
}
__global__ __launch_bounds__(256) void k_bsum(const float* __restrict__ a,const float* __restrict__ b,
                                              float* __restrict__ s,int n){
  int i=blockIdx.x*256+threadIdx.x;
  if(i<n)s[i]=a[i]+b[i];
}

// fold BN scale into GEMM weight (transposed, from fp32) + shift matvec tw[j]=sum_k shift[k]*W[k][j]
__global__ __launch_bounds__(256) void k_foldw(const float* __restrict__ W,
    const float* __restrict__ scale,const float* __restrict__ shift,
    unsigned short* __restrict__ Wt,float* __restrict__ tw){
  __shared__ float red[256];
  int j=blockIdx.x,k=threadIdx.x;
  float w=W[k*256+j];
  Wt[j*256+k]=f2b(w*scale[k]);
  red[k]=w*shift[k];
  __syncthreads();
  for(int off=128;off>0;off>>=1){ if(k<off)red[k]+=red[k+off]; __syncthreads(); }
  if(k==0)tw[j]=red[0];
}

// fold BN scale/shift (per input col) into LSTM ih weights + fused bias
__global__ __launch_bounds__(256) void k_foldlstm(const float* __restrict__ Wih,int K,
    const float* __restrict__ scale,const float* __restrict__ shift,
    const float* __restrict__ bih,const float* __restrict__ bhh,
    unsigned short* __restrict__ Wb,float* __restrict__ bs){
  __shared__ float red[256];
  int m=blockIdx.x,t=threadIdx.x;
  float part=0.f;
  for(int k=t;k<K;k+=256){
    float w=Wih[(long)m*K+k];
    Wb[(long)m*K+k]=f2b(w*scale[k]);
    part+=w*shift[k];
  }
  red[t]=part;
  __syncthreads();
  for(int off=128;off>0;off>>=1){ if(t<off)red[t]+=red[t+off]; __syncthreads(); }
  if(t==0)bs[m]=bih[m]+bhh[m]+red[0];
}

// ---------- dense MFMA GEMM: T8[chunk][node][32](bf16) = A[M,K] @ Bt^T (Bt is [256][K] bf16) ----------
__global__ __launch_bounds__(256,2) void k_gemm_mfma(
    const unsigned short* __restrict__ A,int lda,const unsigned short* __restrict__ Bt,int K,
    unsigned short* __restrict__ Cb){
  __shared__ unsigned short As[2][4096];   // 128 rows x 32 k
  __shared__ unsigned short Bs[2][4096];
  int tid=threadIdx.x;
  int row0=blockIdx.x*128,col0=blockIdx.y*128;
  int lane=tid&63,l15=lane&15,quad=lane>>4;
  int wid=tid>>6,wm=wid>>1,wn=wid&1;
  int sr=tid>>2;                           // staging row 0..63 (per 64-row half)
  int aoff=((tid&3)^((tid>>3)&3))*8;       // pre-swizzled source chunk offset (ushorts)
  int xq=quad^((l15>>1)&3);                // read-side physical chunk
  long ar0=row0+sr;    if(ar0>=NN)ar0=NN-1;
  long ar1=row0+64+sr; if(ar1>=NN)ar1=NN-1;
  const unsigned short* a0p=A+ar0*lda+aoff;
  const unsigned short* a1p=A+ar1*lda+aoff;
  const unsigned short* b0p=Bt+(long)(col0+sr)*K+aoff;
  const unsigned short* b1p=Bt+(long)(col0+64+sr)*K+aoff;
  int lb=wid*512;                          // wave-uniform LDS base (ushorts)
  f32x4 acc[4][4]={};
  int nt=K/32;
  gload16(a0p,&As[0][lb]); gload16(a1p,&As[0][2048+lb]);
  gload16(b0p,&Bs[0][lb]); gload16(b1p,&Bs[0][2048+lb]);
  __syncthreads();
  for(int t=0;t<nt;t++){
    int cur=t&1;
    if(t+1<nt){
      int k0=(t+1)*32;int nxt=cur^1;
      gload16(a0p+k0,&As[nxt][lb]); gload16(a1p+k0,&As[nxt][2048+lb]);
      gload16(b0p+k0,&Bs[nxt][lb]); gload16(b1p+k0,&Bs[nxt][2048+lb]);
    }
    bf8 af[4],bfg[4];
    #pragma unroll
    for(int i=0;i<4;i++){
      af[i] =*(const bf8*)&As[cur][(wm*64+i*16+l15)*32+xq*8];
      bfg[i]=*(const bf8*)&Bs[cur][(wn*64+i*16+l15)*32+xq*8];
    }
    #pragma unroll
    for(int mi=0;mi<4;mi++)
      #pragma unroll
      for(int ni=0;ni<4;ni++)
        acc[mi][ni]=__builtin_amdgcn_mfma_f32_16x16x32_bf16(af[mi],bfg[ni],acc[mi][ni],0,0,0);
    __syncthreads();
  }
  #pragma unroll
  for(int mi=0;mi<4;mi++){
    #pragma unroll
    for(int r=0;r<4;r++){
      int node=row0+wm*64+mi*16+quad*4+r;
      if(node>=NN)continue;
      #pragma unroll
      for(int ni=0;ni<4;ni++){
        int col=col0+wn*64+ni*16+l15;
        Cb[((size_t)(col>>5)*NN+node)*32+(col&31)]=f2b(acc[mi][ni][r]);  // chunk-major
      }
    }
  }
}

// ---------- fused 3-gate LSTM MFMA: h = sig(o)*tanh(sig(i)*tanh(g)) ----------
__global__ __launch_bounds__(256,2) void k_lstm_mfma(
    const unsigned short* __restrict__ A,int lda,int K,
    const unsigned short* __restrict__ Wb,const float* __restrict__ bsum,
    float* __restrict__ Hout,int ldh,unsigned short* __restrict__ Hb){
  __shared__ unsigned short As[2][4096];   // 128 rows x 32 k
  __shared__ unsigned short Bs[2][6144];   // 3 gates x 64 rows x 32 k
  int tid=threadIdx.x;
  int row0=blockIdx.x*128,m0=blockIdx.y*64;
  int lane=tid&63,l15=lane&15,quad=lane>>4;
  int wid=tid>>6,wm=wid>>1,wn=wid&1;
  int sr=tid>>2;
  int aoff=((tid&3)^((tid>>3)&3))*8;
  int xq=quad^((l15>>1)&3);
  long ar0=row0+sr;    if(ar0>=NN)ar0=NN-1;
  long ar1=row0+64+sr; if(ar1>=NN)ar1=NN-1;
  const unsigned short* a0p=A+ar0*lda+aoff;
  const unsigned short* a1p=A+ar1*lda+aoff;
  const unsigned short* wip=Wb+(long)(    m0+sr)*K+aoff;   // i gate
  const unsigned short* wgp=Wb+(long)(512+m0+sr)*K+aoff;   // g gate
  const unsigned short* wop=Wb+(long)(768+m0+sr)*K+aoff;   // o gate
  int lb=wid*512;
  f32x4 ai[4][2]={},ag[4][2]={},ao[4][2]={};
  int nt=K/32;
  gload16(a0p,&As[0][lb]); gload16(a1p,&As[0][2048+lb]);
  gload16(wip,&Bs[0][lb]); gload16(wgp,&Bs[0][2048+lb]); gload16(wop,&Bs[0][4096+lb]);
  __syncthreads();
  for(int t=0;t<nt;t++){
    int cur=t&1;
    if(t+1<nt){
      int k0=(t+1)*32;int nxt=cur^1;
      gload16(a0p+k0,&As[nxt][lb]); gload16(a1p+k0,&As[nxt][2048+lb]);
      gload16(wip+k0,&Bs[nxt][lb]); gload16(wgp+k0,&Bs[nxt][2048+lb]); gload16(wop+k0,&Bs[nxt][4096+lb]);
    }
    bf8 af[4],bi[2],bg[2],bo[2];
    #pragma unroll
    for(int i=0;i<4;i++)af[i]=*(const bf8*)&As[cur][(wm*64+i*16+l15)*32+xq*8];
    #pragma unroll
    for(int ni=0;ni<2;ni++){
      int rr=wn*32+ni*16+l15;
      bi[ni]=*(const bf8*)&Bs[cur][(    rr)*32+xq*8];
      bg[ni]=*(const bf8*)&Bs[cur][( 64+rr)*32+xq*8];
      bo[ni]=*(const bf8*)&Bs[cur][(128+rr)*32+xq*8];
    }
    #pragma unroll
    for(int mi=0;mi<4;mi++)
      #pragma unroll
      for(int ni=0;ni<2;ni++){
        ai[mi][ni]=__builtin_amdgcn_mfma_f32_16x16x32_bf16(af[mi],bi[ni],ai[mi][ni],0,0,0);
        ag[mi][ni]=__builtin_amdgcn_mfma_f32_16x16x32_bf16(af[mi],bg[ni],ag[mi][ni],0,0,0);
        ao[mi][ni]=__builtin_amdgcn_mfma_f32_16x16x32_bf16(af[mi],bo[ni],ao[mi][ni],0,0,0);
      }
    __syncthreads();
  }
  #pragma unroll
  for(int ni=0;ni<2;ni++){
    int m=m0+wn*32+ni*16+l15;
    float b_i=bsum[m],b_g=bsum[512+m],b_o=bsum[768+m];
    #pragma unroll
    for(int mi=0;mi<4;mi++){
      #pragma unroll
      for(int r=0;r<4;r++){
        int node=row0+wm*64+mi*16+quad*4+r;
        if(node>=NN)continue;
        float gi=ai[mi][ni][r]+b_i;
        float gg=ag[mi][ni][r]+b_g;
        float go=ao[mi][ni][r]+b_o;
        float c=fsigm(gi)*ftanh(gg);
        float h=fsigm(go)*ftanh(c);
        Hout[(long)node*ldh+m]=h;
        if(Hb)Hb[(long)node*256+m]=f2b(h);
      }
    }
  }
}

// ---------- chunked SpMM v2: T8[chunk][node][32] bf16, chunk = blockIdx&7 -> XCD-pinned L2 slice ----------
// Wave = 16 row-groups x 4 lanes; lane gathers 16B (8 cols). 64 rows/block, grid 8 x 782.
__global__ __launch_bounds__(256) void k_spmm8(const unsigned short* __restrict__ T8,
    const int* __restrict__ row_ptr,const int2* __restrict__ csr_sw,
    const float* __restrict__ dinv,const float* __restrict__ bias,const float* __restrict__ tw,
    unsigned short* __restrict__ Xb,float* colsum,float* colsq){
  __shared__ float s_sum[4][32];
  __shared__ float s_sq[4][32];
  int tid=threadIdx.x;
  int lane=tid&63,wv=tid>>6;
  int g=lane>>2,li=lane&3;            // 16 row-groups x 4 lanes
  int chunk=blockIdx.x&7;
  int rowblk=blockIdx.x>>3;
  int r=rowblk*64+wv*16+g;
  bool valid=r<NN;
  int rc=valid?r:0;
  int co=li*8;                         // column offset within chunk (ushorts)
  int c0=chunk*32+co;
  const unsigned short* Tc=T8+(size_t)chunk*NN*32;
  int p0=row_ptr[rc],p1=row_ptr[rc+1];
  int len=valid?(p1-p0):0;
  float di=dinv[rc],ws=di*di;
  float rs=ws;
  float acc[8];
  { bf8 t=*(const bf8*)&Tc[(u32)rc*32+co];
    #pragma unroll
    for(int e=0;e<8;e++)acc[e]=ws*b2f((unsigned short)t[e]);
  }
  int j=0;
  for(;j+2<=len;j+=2){
    u64 ev0=__builtin_nontemporal_load((const u64*)&csr_sw[p0+j]);
    u64 ev1=__builtin_nontemporal_load((const u64*)&csr_sw[p0+j+1]);
    int s0=(int)(u32)ev0; float w0=__int_as_float((int)(ev0>>32));
    int s1=(int)(u32)ev1; float w1=__int_as_float((int)(ev1>>32));
    s0=min(max(s0,0),NN-1); s1=min(max(s1,0),NN-1);
    bf8 t0=*(const bf8*)&Tc[(u32)s0*32+co];
    bf8 t1=*(const bf8*)&Tc[(u32)s1*32+co];
    #pragma unroll
    for(int e=0;e<8;e++)acc[e]+=w0*b2f((unsigned short)t0[e]);
    #pragma unroll
    for(int e=0;e<8;e++)acc[e]+=w1*b2f((unsigned short)t1[e]);
    rs+=w0+w1;
  }
  if(j<len){
    u64 ev=__builtin_nontemporal_load((const u64*)&csr_sw[p0+j]);
    int s=(int)(u32)ev; float wg=__int_as_float((int)(ev>>32));
    s=min(max(s,0),NN-1);
    bf8 t=*(const bf8*)&Tc[(u32)s*32+co];
    #pragma unroll
    for(int e=0;e<8;e++)acc[e]+=wg*b2f((unsigned short)t[e]);
    rs+=wg;
  }
  float4 bA=*(const float4*)&bias[c0],bB=*(const float4*)&bias[c0+4];
  float4 tA=make_float4(0.f,0.f,0.f,0.f),tB=tA;
  if(tw){ tA=*(const float4*)&tw[c0]; tB=*(const float4*)&tw[c0+4]; }
  float o[8];
  o[0]=fmaxf(acc[0]+rs*tA.x+bA.x,0.f);
  o[1]=fmaxf(acc[1]+rs*tA.y+bA.y,0.f);
  o[2]=fmaxf(acc[2]+rs*tA.z+bA.z,0.f);
  o[3]=fmaxf(acc[3]+rs*tA.w+bA.w,0.f);
  o[4]=fmaxf(acc[4]+rs*tB.x+bB.x,0.f);
  o[5]=fmaxf(acc[5]+rs*tB.y+bB.y,0.f);
  o[6]=fmaxf(acc[6]+rs*tB.z+bB.z,0.f);
  o[7]=fmaxf(acc[7]+rs*tB.w+bB.w,0.f);
  if(valid){
    bf8 ov;
    #pragma unroll
    for(int e=0;e<8;e++)ov[e]=(short)f2b(o[e]);
    __builtin_nontemporal_store(ov,(bf8*)&Xb[(size_t)r*512+c0]);
  }
  // stats: zero invalid rows, reduce over 16 groups via shfl, then waves via LDS
  float sv[8],qv[8];
  #pragma unroll
  for(int e=0;e<8;e++){ float v=valid?o[e]:0.f; sv[e]=v; qv[e]=v*v; }
  #pragma unroll
  for(int m=4;m<64;m<<=1){
    #pragma unroll
    for(int e=0;e<8;e++){ sv[e]+=__shfl_xor(sv[e],m,64); qv[e]+=__shfl_xor(qv[e],m,64); }
  }
  if(g==0){
    #pragma unroll
    for(int e=0;e<8;e++){ s_sum[wv][co+e]=sv[e]; s_sq[wv][co+e]=qv[e]; }
  }
  __syncthreads();
  if(tid<32){
    float a=s_sum[0][tid]+s_sum[1][tid]+s_sum[2][tid]+s_sum[3][tid];
    float q=s_sq[0][tid]+s_sq[1][tid]+s_sq[2][tid]+s_sq[3][tid];
    atomicAdd(&colsum[chunk*32+tid],a);
    atomicAdd(&colsq[chunk*32+tid],q);
  }
}

__global__ __launch_bounds__(256) void k_bnfin(const float* __restrict__ gamma,const float* __restrict__ beta,
    float* colsum,float* colsq,float* scale,float* shift){
  int c=threadIdx.x;
  float mu=colsum[c]/(float)NN;
  float var=colsq[c]/(float)NN-mu*mu;
  float r=rsqrtf(var+1e-5f);
  float sc=r*gamma[c];
  scale[c]=sc;
  shift[c]=beta[c]-mu*sc;
  colsum[c]=0.f;colsq[c]=0.f;
}

__global__ __launch_bounds__(256) void k_copy_out(const float* __restrict__ src,
    float* __restrict__ out,int colofs){
  long idx=(long)blockIdx.x*256+threadIdx.x;
  long r=idx>>6;int cc=(int)(idx&63)*4;
  if(r<NN)*(float4*)&out[r*768+colofs+cc]=*(const float4*)&src[r*256+cc];
}

extern "C" void kernel_launch(void* const* d_in,const int* in_sizes,int n_in,
                              void* d_out,int out_size,void* d_ws,size_t ws_size,
                              hipStream_t stream){
  const float* x   =(const float*)d_in[0];
  const int*   ei  =(const int*)  d_in[1];
  const float* ew  =(const float*)d_in[2];
  const float* W1  =(const float*)d_in[3];
  const float* b1  =(const float*)d_in[4];
  const float* W2  =(const float*)d_in[5];
  const float* b2  =(const float*)d_in[6];
  const float* g1  =(const float*)d_in[7];
  const float* be1 =(const float*)d_in[8];
  const float* g2  =(const float*)d_in[9];
  const float* be2 =(const float*)d_in[10];
  const float* Wih1=(const float*)d_in[11];
  const float* bih1=(const float*)d_in[13];
  const float* bhh1=(const float*)d_in[14];
  const float* Wih2=(const float*)d_in[15];
  const float* bih2=(const float*)d_in[17];
  const float* bhh2=(const float*)d_in[18];
  float* out=(float*)d_out;

  char* w=(char*)d_ws;
  auto alloc=[&](size_t bytes)->char*{char* p=w;w+=(bytes+255)&~(size_t)255;return p;};
  float* deg    =(float*)alloc((size_t)NN*4);
  float* dinv   =(float*)alloc((size_t)NN*4);
  int*   cnt    =(int*)  alloc((size_t)NN*4);
  int*   row_ptr=(int*)  alloc((size_t)(NN+1)*4);
  int*   cursor =(int*)  alloc((size_t)NN*4);
  int2*  csr_sw =(int2*) alloc((size_t)NE*8);
  int*   bsum_s =(int*)  alloc(64*4);
  int*   bbase  =(int*)  alloc(64*4);
  float* colsum =(float*)alloc(256*4);
  float* colsq  =(float*)alloc(256*4);
  float* scale  =(float*)alloc(512*4);
  float* shift  =(float*)alloc(512*4);
  float* tw     =(float*)alloc(256*4);
  unsigned short* Xcb =(unsigned short*)alloc((size_t)NN*512*2);  // [h1pre|h2pre] bf16, ld 512
  unsigned short* TbH =(unsigned short*)alloc((size_t)NN*256*2);  // chunk-major GEMM out / LSTM1 hidden (row-major, aliased)
  unsigned short* xb  =(unsigned short*)alloc((size_t)NN*256*2);  // x cast to bf16
  unsigned short* Wt1 =(unsigned short*)alloc(256*256*2);
  unsigned short* Wt2 =(unsigned short*)alloc(256*256*2);
  unsigned short* Wb1 =(unsigned short*)alloc((size_t)1024*512*2);
  unsigned short* Wb2 =(unsigned short*)alloc((size_t)1024*256*2);
  float* bs1 =(float*)alloc(1024*4);
  float* bs2 =(float*)alloc(1024*4);

  int nb=(NN+255)/256;
  int nsc=(NN+1023)/1024;   // 49
  k_init<<<nb,256,0,stream>>>(deg,cnt,colsum,colsq);
  k_deg<<<(NE+255)/256,256,0,stream>>>(ei,ew,deg,cnt);
  k_dinv<<<nb,256,0,stream>>>(deg,dinv);
  k_scan1<<<nsc,1024,0,stream>>>(cnt,row_ptr,bsum_s);
  k_scan2<<<1,64,0,stream>>>(bsum_s,bbase,row_ptr,nsc);
  k_scan3<<<nb,256,0,stream>>>(row_ptr,cursor,bbase);
  k_scatter<<<(NE+255)/256,256,0,stream>>>(ei,ew,dinv,cursor,csr_sw);

  k_wt<<<256,256,0,stream>>>(W1,Wt1);
  k_cast<<<12500,256,0,stream>>>(x,xb);      // 50000*256/4 threads exactly
  k_f2b<<<(1024*256+255)/256,256,0,stream>>>(Wih2,Wb2,1024*256);
  k_bsum<<<4,256,0,stream>>>(bih2,bhh2,bs2,1024);

  int ngx=(NN+127)/128;
  dim3 gd(ngx,2);   // dense GEMM: 256 cols / 128
  dim3 gl(ngx,4);   // lstm: 256 h-cols / 64
  int nspmm=8*((NN+63)/64);   // 8 chunks x 782 row-blocks

  // layer 1 (Xcb[0:256) holds PRE-BN relu'd h1; BN folded into downstream consumers)
  k_gemm_mfma<<<gd,256,0,stream>>>(xb,256,Wt1,256,TbH);
  k_spmm8<<<nspmm,256,0,stream>>>(TbH,row_ptr,csr_sw,dinv,b1,nullptr,Xcb+0,colsum,colsq);
  k_bnfin<<<1,256,0,stream>>>(g1,be1,colsum,colsq,scale,shift);
  // fold BN1 into GEMM2 weights; shift contribution handled via rowsum*tw in spmm2
  k_foldw<<<256,256,0,stream>>>(W2,scale,shift,Wt2,tw);
  // layer 2 (Xcb[256:512) holds PRE-BN relu'd h2)
  k_gemm_mfma<<<gd,256,0,stream>>>(Xcb,512,Wt2,256,TbH);
  k_spmm8<<<nspmm,256,0,stream>>>(TbH,row_ptr,csr_sw,dinv,b2,tw,Xcb+256,colsum,colsq);
  k_bnfin<<<1,256,0,stream>>>(g2,be2,colsum,colsq,scale+256,shift+256);
  // fold BN1|BN2 (concat cols) into LSTM1 ih weights + fused bias
  k_foldlstm<<<1024,256,0,stream>>>(Wih1,512,scale,shift,bih1,bhh1,Wb1,bs1);
  // LSTM1: A=Xcb [N,512] pre-BN -> out[0:256) fp32 + TbH bf16 (TbH dead after spmm2)
  k_lstm_mfma<<<gl,256,0,stream>>>(Xcb,512,512,Wb1,bs1,out+0,768,TbH);
  // LSTM2: A=TbH [N,256] -> out[256:512)
  k_lstm_mfma<<<gl,256,0,stream>>>(TbH,256,256,Wb2,bs2,out+256,768,nullptr);
  // x passthrough
  k_copy_out<<<12500,256,0,stream>>>(x,out,512);
}